// Round 7
// baseline (1169.119 us; speedup 1.0000x reference)
//
#include <hip/hip_runtime.h>

typedef unsigned short u16;
typedef __attribute__((ext_vector_type(4))) float f32x4;
typedef __attribute__((ext_vector_type(4))) float float4v;
typedef __attribute__((ext_vector_type(8))) short s16x8;
typedef __attribute__((ext_vector_type(8))) u16 u16x8;
typedef __attribute__((ext_vector_type(4))) u16 u16x4;

__device__ __forceinline__ float bf2f(u16 u) {
  union { unsigned int i; float f; } v; v.i = ((unsigned int)u) << 16; return v.f;
}
__device__ __forceinline__ u16 f2bf(float f) {
  union { float f; unsigned int i; } v; v.f = f;
  unsigned int i = v.i;
  return (u16)((i + 0x7FFFu + ((i >> 16) & 1u)) >> 16);
}

#define GLOBAL_AS __attribute__((address_space(1)))
#define LDS_AS __attribute__((address_space(3)))

__device__ __forceinline__ void async_copy16(const void* gsrc, void* ldst) {
  __builtin_amdgcn_global_load_lds((const GLOBAL_AS unsigned int*)gsrc,
                                   (LDS_AS unsigned int*)ldst, 16, 0, 0);
}

// bijective XCD swizzle (m204) — works for any nwg
__device__ __forceinline__ int xcd_swz(int wg, int nwg) {
  int q = nwg >> 3, r = nwg & 7;
  int xcd = wg & 7, i = wg >> 3;
  return (xcd < r ? xcd * (q + 1) : r * (q + 1) + (xcd - r) * q) + i;
}

// ---------------------------------------------------------------------------
__global__ __launch_bounds__(256) void zero_f32(float* __restrict__ p, int n) {
  int i = blockIdx.x * 256 + threadIdx.x;
  if (i < n) p[i] = 0.f;
}

// cast f32 -> bf16 (n multiple of 4)
__global__ __launch_bounds__(256) void cast_bf(const float* __restrict__ src,
                                               u16* __restrict__ dst, long n) {
  long i = ((long)blockIdx.x * 256 + threadIdx.x) * 4;
  if (i + 3 < n) {
    float4v v = *(const float4v*)&src[i];
    u16x4 o;
    o[0] = f2bf(v[0]); o[1] = f2bf(v[1]); o[2] = f2bf(v[2]); o[3] = f2bf(v[3]);
    *(u16x4*)&dst[i] = o;
  }
}

// ---------------------------------------------------------------------------
// shared GEMM compute body helpers (LDS layouts identical across variants):
// As/Bs are 128x64 bf16, XOR-swizzled: elem (row, e) lives at
// row*64 + ((g ^ (row&7))<<3) + (e&7), g = e>>3.

// reg-stage a 128x64 bf16 B-tile from an f32 row-major source (swizzled write)
__device__ __forceinline__ void stage_B_f32(const float* __restrict__ Wf,
                                            int rowsMax, int ldw, int k0,
                                            u16* Bs, int tid) {
#pragma unroll
  for (int it = 0; it < 8; ++it) {
    int i = it * 256 + tid;          // one float4 (4 elems) each, 2048 total
    int row = i >> 4, j = i & 15, e0 = j << 2;
    int rr = row <= rowsMax ? row : rowsMax;
    float4v v = *(const float4v*)&Wf[(size_t)rr * ldw + k0 + e0];
    u16x4 b;
    b[0] = f2bf(v[0]); b[1] = f2bf(v[1]); b[2] = f2bf(v[2]); b[3] = f2bf(v[3]);
    int g = e0 >> 3, o = e0 & 7;
    *(u16x4*)&Bs[row * 64 + ((g ^ (row & 7)) << 3) + o] = b;
  }
}

// ---------------------------------------------------------------------------
// GEMM1 with split store: C[M,8512] = A[M,2048] @ W[8512,2048]^T
// cols <4096 -> zbuf; 4096..8447 -> xdt[.][0..4351]; 8448.. -> xdt[.][4352..]
template <bool F32W>
__global__ __launch_bounds__(256, 2)
void gemm_zx(const u16* __restrict__ A, const u16* __restrict__ Bbf,
             const float* __restrict__ Bf32,
             u16* __restrict__ zbuf, u16* __restrict__ xdt,
             int M, int N, int K, int nbn) {
  constexpr int BK = 64;
  __shared__ u16 As[128 * BK];
  __shared__ u16 Bs[128 * BK];
  int nwg = gridDim.x;
  int wg = xcd_swz(blockIdx.x, nwg);
  int bm = wg / nbn, bn = wg - bm * nbn;
  int tid = threadIdx.x, lane = tid & 63, w = tid >> 6;
  int wr = w >> 1, wc = w & 1;
  f32x4 acc[4][4] = {};
  const u16* Ab = A + (size_t)bm * 128 * K;
  int maxBrow = N - bn * 128 - 1;

  for (int k0 = 0; k0 < K; k0 += BK) {
#pragma unroll
    for (int j = 0; j < 4; ++j) {
      int t16 = (w * 4 + j) * 64 + lane;
      int row = t16 >> 3, c8 = t16 & 7;
      int kkA = ((c8 ^ (row & 7)) << 3);
      async_copy16(Ab + (size_t)row * K + k0 + kkA, &As[(w * 4 + j) * 512]);
      if constexpr (!F32W) {
        const u16* Bb = Bbf + (size_t)bn * 128 * K;
        int rowB = row <= maxBrow ? row : maxBrow;
        int kkB = ((c8 ^ (rowB & 7)) << 3);
        async_copy16(Bb + (size_t)rowB * K + k0 + kkB, &Bs[(w * 4 + j) * 512]);
      }
    }
    if constexpr (F32W)
      stage_B_f32(Bf32 + (size_t)bn * 128 * K, maxBrow, K, k0, Bs, tid);
    __syncthreads();
#pragma unroll
    for (int kt = 0; kt < 2; ++kt) {
      int c8 = kt * 4 + (lane >> 4);
      s16x8 a[4], bfr[4];
#pragma unroll
      for (int mi = 0; mi < 4; ++mi) {
        int row = wr * 64 + mi * 16 + (lane & 15);
        a[mi] = *(const s16x8*)&As[row * BK + ((c8 ^ (row & 7)) << 3)];
      }
#pragma unroll
      for (int ni = 0; ni < 4; ++ni) {
        int row = wc * 64 + ni * 16 + (lane & 15);
        bfr[ni] = *(const s16x8*)&Bs[row * BK + ((c8 ^ (row & 7)) << 3)];
      }
#pragma unroll
      for (int mi = 0; mi < 4; ++mi)
#pragma unroll
        for (int ni = 0; ni < 4; ++ni)
          acc[mi][ni] = __builtin_amdgcn_mfma_f32_16x16x32_bf16(a[mi], bfr[ni], acc[mi][ni], 0, 0, 0);
    }
    __syncthreads();
  }
  int crow0 = bm * 128 + wr * 64;
  int ccol0 = bn * 128 + wc * 64;
#pragma unroll
  for (int mi = 0; mi < 4; ++mi) {
#pragma unroll
    for (int ni = 0; ni < 4; ++ni) {
      int col = ccol0 + ni * 16 + (lane & 15);
#pragma unroll
      for (int i = 0; i < 4; ++i) {
        size_t row = crow0 + mi * 16 + (lane >> 4) * 4 + i;
        u16 v = f2bf(acc[mi][ni][i]);
        if (col < 4096)       zbuf[row * 4096 + col] = v;
        else if (col < 8448)  xdt[row * 4416 + (col - 4096)] = v;
        else if (col < 8512)  xdt[row * 4416 + 4352 + (col - 8448)] = v;
      }
    }
  }
}

// ---------------------------------------------------------------------------
// plain GEMM: C[M,N] = A[M,K] @ B[N,K]^T, f32 out
template <bool F32W>
__global__ __launch_bounds__(256, 2)
void gemm_bt(const u16* __restrict__ A, const u16* __restrict__ Bbf,
             const float* __restrict__ Bf32,
             float* __restrict__ C, int M, int N, int K, int nbn) {
  constexpr int BK = 64;
  __shared__ u16 As[128 * BK];
  __shared__ u16 Bs[128 * BK];
  int nwg = gridDim.x;
  int wg = xcd_swz(blockIdx.x, nwg);
  int bm = wg / nbn, bn = wg - bm * nbn;
  int tid = threadIdx.x, lane = tid & 63, w = tid >> 6;
  int wr = w >> 1, wc = w & 1;
  f32x4 acc[4][4] = {};
  const u16* Ab = A + (size_t)bm * 128 * K;

  for (int k0 = 0; k0 < K; k0 += BK) {
#pragma unroll
    for (int j = 0; j < 4; ++j) {
      int t16 = (w * 4 + j) * 64 + lane;
      int row = t16 >> 3, c8 = t16 & 7;
      int kk = ((c8 ^ (row & 7)) << 3);
      async_copy16(Ab + (size_t)row * K + k0 + kk, &As[(w * 4 + j) * 512]);
      if constexpr (!F32W) {
        const u16* Bb = Bbf + (size_t)bn * 128 * K;
        async_copy16(Bb + (size_t)row * K + k0 + kk, &Bs[(w * 4 + j) * 512]);
      }
    }
    if constexpr (F32W)
      stage_B_f32(Bf32 + (size_t)bn * 128 * K, 127, K, k0, Bs, tid);
    __syncthreads();
#pragma unroll
    for (int kt = 0; kt < 2; ++kt) {
      int c8 = kt * 4 + (lane >> 4);
      s16x8 a[4], bfr[4];
#pragma unroll
      for (int mi = 0; mi < 4; ++mi) {
        int row = wr * 64 + mi * 16 + (lane & 15);
        a[mi] = *(const s16x8*)&As[row * BK + ((c8 ^ (row & 7)) << 3)];
      }
#pragma unroll
      for (int ni = 0; ni < 4; ++ni) {
        int row = wc * 64 + ni * 16 + (lane & 15);
        bfr[ni] = *(const s16x8*)&Bs[row * BK + ((c8 ^ (row & 7)) << 3)];
      }
#pragma unroll
      for (int mi = 0; mi < 4; ++mi)
#pragma unroll
        for (int ni = 0; ni < 4; ++ni)
          acc[mi][ni] = __builtin_amdgcn_mfma_f32_16x16x32_bf16(a[mi], bfr[ni], acc[mi][ni], 0, 0, 0);
    }
    __syncthreads();
  }
  size_t crow0 = (size_t)bm * 128 + wr * 64;
  int ccol0 = bn * 128 + wc * 64;
#pragma unroll
  for (int mi = 0; mi < 4; ++mi) {
#pragma unroll
    for (int ni = 0; ni < 4; ++ni) {
      int col = ccol0 + ni * 16 + (lane & 15);
#pragma unroll
      for (int i = 0; i < 4; ++i) {
        size_t row = crow0 + mi * 16 + (lane >> 4) * 4 + i;
        C[row * N + col] = acc[mi][ni][i];
      }
    }
  }
}

// ---------------------------------------------------------------------------
// dt = softplus(dtproj + bias); per-chunk cumsum of dt*A. Segment-local.
__global__ __launch_bounds__(64)
void dt_cs_kernel(const u16* __restrict__ xdt, const float* __restrict__ dt_bias,
                  const float* __restrict__ A_log, float* __restrict__ dtp,
                  float* __restrict__ acs, float* __restrict__ alast) {
  int c = blockIdx.x;
  int hh = threadIdx.x;
  float bias = dt_bias[hh];
  float A = -__expf(A_log[hh]);
  float run = 0.f;
  size_t base = (size_t)c * 64;
  for (int l = 0; l < 64; ++l) {
    float xv = bf2f(xdt[(base + l) * 4416 + 4352 + hh]) + bias;
    float d = (xv > 20.f) ? xv : log1pf(__expf(xv));
    run += d * A;
    dtp[(base + l) * 64 + hh] = d;
    acs[(base + l) * 64 + hh] = run;
  }
  alast[c * 64 + hh] = run;
}

// ---------------------------------------------------------------------------
// causal depthwise conv (width 4) + silu; tail = previous 3 pre-conv rows
__global__ __launch_bounds__(256)
void conv_silu(const u16* __restrict__ xdt, const u16* __restrict__ tail,
               const float* __restrict__ cw, const float* __restrict__ cb,
               u16* __restrict__ xbc) {
  int l = blockIdx.x;
  for (int i = threadIdx.x; i < 4352; i += 256) {
    float acc = cb[i];
#pragma unroll
    for (int j = 0; j < 4; ++j) {
      int lj = l - 3 + j;
      float xv = (lj >= 0) ? bf2f(xdt[(size_t)lj * 4416 + i])
                           : bf2f(tail[(lj + 3) * 4352 + i]);
      acc += xv * cw[i * 4 + j];
    }
    float s = acc / (1.0f + __expf(-acc));
    xbc[(size_t)l * 4352 + i] = f2bf(s);
  }
}

// save last 3 pre-conv rows for next segment
__global__ __launch_bounds__(256)
void save_tail(const u16* __restrict__ xdt, u16* __restrict__ tail, int Ls) {
  for (int i = threadIdx.x; i < 3 * 4352; i += 256) {
    int j = i / 4352, ii = i - j * 4352;
    tail[i] = xdt[(size_t)(Ls - 3 + j) * 4416 + ii];
  }
}

// ---------------------------------------------------------------------------
// SSD intra-chunk (segment-local): per (h,c): S = C@B^T (decay-masked),
// Y_diag = S@xdt, chunk_state[p][n] = sum_l xdt[l,p]*decay[l]*B[l,n].
__global__ __launch_bounds__(256, 2)
void ssd_intra(const u16* __restrict__ xbc, const float* __restrict__ dtp,
               const float* __restrict__ acs, u16* __restrict__ ydiag,
               u16* __restrict__ states) {
  constexpr int LDC = 136, LDT = 72;
  __shared__ u16 Cs[64 * LDC];
  __shared__ u16 Bs[64 * LDC];
  __shared__ u16 BTd[128 * LDT];
  __shared__ u16 xdtT[64 * LDT];
  __shared__ u16 Sl[64 * LDT];
  __shared__ float csL[64], dtL[64];
  int h = blockIdx.x, c = blockIdx.y;
  int tid = threadIdx.x, lane = tid & 63, w = tid >> 6;
  size_t rowbase = (size_t)c * 64;
  if (tid < 64) csL[tid] = acs[(rowbase + tid) * 64 + h];
  else if (tid < 128) dtL[tid - 64] = dtp[(rowbase + tid - 64) * 64 + h];
  __syncthreads();
  float cs_last = csL[63];
  for (int i = tid; i < 1024; i += 256) {
    int s = i >> 4, n = (i & 15) << 3;
    const u16* srcB = xbc + (rowbase + s) * 4352 + 4096 + n;
    *(u16x8*)&Bs[s * LDC + n] = *(const u16x8*)srcB;
    *(u16x8*)&Cs[s * LDC + n] = *(const u16x8*)(srcB + 128);
  }
  for (int i = tid; i < 512; i += 256) {
    int s = i >> 3, p0 = (i & 7) << 3;
    u16x8 xv = *(const u16x8*)(xbc + (rowbase + s) * 4352 + h * 64 + p0);
    float dts = dtL[s];
#pragma unroll
    for (int j = 0; j < 8; ++j) xdtT[(p0 + j) * LDT + s] = f2bf(bf2f(xv[j]) * dts);
  }
  __syncthreads();
  for (int i = tid; i < 8192; i += 256) {
    int n = i & 127, s = i >> 7;
    float dec = __expf(cs_last - csL[s]);
    BTd[n * LDT + s] = f2bf(bf2f(Bs[s * LDC + n]) * dec);
  }
  // S = C @ B^T
  f32x4 accS[4] = {};
#pragma unroll
  for (int kt = 0; kt < 4; ++kt) {
    int kk = kt * 32 + (lane >> 4) * 8;
    s16x8 a = *(const s16x8*)&Cs[(w * 16 + (lane & 15)) * LDC + kk];
#pragma unroll
    for (int nf = 0; nf < 4; ++nf) {
      s16x8 bb = *(const s16x8*)&Bs[(nf * 16 + (lane & 15)) * LDC + kk];
      accS[nf] = __builtin_amdgcn_mfma_f32_16x16x32_bf16(a, bb, accS[nf], 0, 0, 0);
    }
  }
  int lbase = w * 16 + ((lane >> 4) << 2);
#pragma unroll
  for (int nf = 0; nf < 4; ++nf) {
    int s = nf * 16 + (lane & 15);
    float cs_s = csL[s];
#pragma unroll
    for (int i = 0; i < 4; ++i) {
      int l = lbase + i;
      float v = (s <= l) ? accS[nf][i] * __expf(csL[l] - cs_s) : 0.0f;
      Sl[l * LDT + s] = f2bf(v);
    }
  }
  __syncthreads();
  // Y_diag = S @ xdt
  f32x4 accY[4] = {};
#pragma unroll
  for (int kt = 0; kt < 2; ++kt) {
    int kk = kt * 32 + (lane >> 4) * 8;
    s16x8 a = *(const s16x8*)&Sl[(w * 16 + (lane & 15)) * LDT + kk];
#pragma unroll
    for (int pf = 0; pf < 4; ++pf) {
      s16x8 bb = *(const s16x8*)&xdtT[(pf * 16 + (lane & 15)) * LDT + kk];
      accY[pf] = __builtin_amdgcn_mfma_f32_16x16x32_bf16(a, bb, accY[pf], 0, 0, 0);
    }
  }
#pragma unroll
  for (int pf = 0; pf < 4; ++pf) {
#pragma unroll
    for (int i = 0; i < 4; ++i) {
      int l = lbase + i;
      int p = pf * 16 + (lane & 15);
      ydiag[(rowbase + l) * 4096 + h * 64 + p] = f2bf(accY[pf][i]);
    }
  }
  // chunk_state
  f32x4 accT[4][2] = {};
#pragma unroll
  for (int kt = 0; kt < 2; ++kt) {
    int kk = kt * 32 + (lane >> 4) * 8;
    s16x8 a[4], bb[2];
#pragma unroll
    for (int mf = 0; mf < 4; ++mf)
      a[mf] = *(const s16x8*)&xdtT[(mf * 16 + (lane & 15)) * LDT + kk];
#pragma unroll
    for (int nj = 0; nj < 2; ++nj)
      bb[nj] = *(const s16x8*)&BTd[((w * 2 + nj) * 16 + (lane & 15)) * LDT + kk];
#pragma unroll
    for (int mf = 0; mf < 4; ++mf)
#pragma unroll
      for (int nj = 0; nj < 2; ++nj)
        accT[mf][nj] = __builtin_amdgcn_mfma_f32_16x16x32_bf16(a[mf], bb[nj], accT[mf][nj], 0, 0, 0);
  }
  size_t sb = ((size_t)c * 64 + h) * 8192;
#pragma unroll
  for (int mf = 0; mf < 4; ++mf) {
#pragma unroll
    for (int nj = 0; nj < 2; ++nj) {
      int n = (w * 2 + nj) * 16 + (lane & 15);
#pragma unroll
      for (int i = 0; i < 4; ++i) {
        int p = mf * 16 + ((lane >> 4) << 2) + i;
        states[sb + p * 128 + n] = f2bf(accT[mf][nj][i]);
      }
    }
  }
}

// ---------------------------------------------------------------------------
// inter-chunk scan with cross-segment carry (f32)
__global__ __launch_bounds__(256)
void state_scan(u16* __restrict__ states, const float* __restrict__ alast,
                float* __restrict__ carry, int Cn) {
  int sl = blockIdx.x, h = blockIdx.y;
  int tid = threadIdx.x;
  size_t off = (size_t)h * 8192 + sl * 2048 + tid * 8;
  const size_t cstride = 524288;  // 64*8192
  float r[8];
#pragma unroll
  for (int j = 0; j < 8; ++j) r[j] = carry[off + j];
  for (int c = 0; c < Cn; ++c) {
    float dec = __expf(alast[c * 64 + h]);
    size_t idx = (size_t)c * cstride + off;
    u16x8 v = *(u16x8*)&states[idx];
    u16x8 o;
#pragma unroll
    for (int j = 0; j < 8; ++j) { o[j] = f2bf(r[j]); r[j] = r[j] * dec + bf2f(v[j]); }
    *(u16x8*)&states[idx] = o;
  }
#pragma unroll
  for (int j = 0; j < 8; ++j) carry[off + j] = r[j];
}

// ---------------------------------------------------------------------------
// Y_off = C @ state, + Y_diag + x*D, * silu(z)
__global__ __launch_bounds__(256, 2)
void ssd_inter(const u16* __restrict__ xbc, const u16* __restrict__ states,
               const float* __restrict__ acs, const u16* __restrict__ zbuf,
               const float* __restrict__ Dp, u16* __restrict__ y) {
  constexpr int LDC = 136;
  __shared__ u16 Cs[64 * LDC];
  __shared__ u16 St[64 * LDC];
  __shared__ float csL[64];
  int h = blockIdx.x, c = blockIdx.y;
  int tid = threadIdx.x, lane = tid & 63, w = tid >> 6;
  size_t rowbase = (size_t)c * 64;
  size_t sb = ((size_t)c * 64 + h) * 8192;
  if (tid < 64) csL[tid] = acs[(rowbase + tid) * 64 + h];
  for (int i = tid; i < 1024; i += 256) {
    int s = i >> 4, n = (i & 15) << 3;
    *(u16x8*)&Cs[s * LDC + n] = *(const u16x8*)(xbc + (rowbase + s) * 4352 + 4224 + n);
    *(u16x8*)&St[s * LDC + n] = *(const u16x8*)(states + sb + s * 128 + n);
  }
  __syncthreads();
  f32x4 acc[4] = {};
#pragma unroll
  for (int kt = 0; kt < 4; ++kt) {
    int kk = kt * 32 + (lane >> 4) * 8;
    s16x8 a = *(const s16x8*)&Cs[(w * 16 + (lane & 15)) * LDC + kk];
#pragma unroll
    for (int pf = 0; pf < 4; ++pf) {
      s16x8 bb = *(const s16x8*)&St[(pf * 16 + (lane & 15)) * LDC + kk];
      acc[pf] = __builtin_amdgcn_mfma_f32_16x16x32_bf16(a, bb, acc[pf], 0, 0, 0);
    }
  }
  float Dh = Dp[h];
  int lbase = w * 16 + ((lane >> 4) << 2);
#pragma unroll
  for (int pf = 0; pf < 4; ++pf) {
    int p = pf * 16 + (lane & 15);
#pragma unroll
    for (int i = 0; i < 4; ++i) {
      int l = lbase + i;
      size_t row = rowbase + l;
      float decay = __expf(csL[l]);
      float xv = bf2f(xbc[row * 4352 + h * 64 + p]);
      float zv = bf2f(zbuf[row * 4096 + h * 64 + p]);
      size_t yi = row * 4096 + h * 64 + p;
      float yd = bf2f(y[yi]);
      float val = acc[pf][i] * decay + yd + xv * Dh;
      float sz = zv / (1.0f + __expf(-zv));
      y[yi] = f2bf(val * sz);
    }
  }
}

// ---------------------------------------------------------------------------
// RMSNorm over 4096
__global__ __launch_bounds__(256)
void rmsnorm_bf(const u16* __restrict__ yg, const float* __restrict__ nw,
                u16* __restrict__ out) {
  __shared__ float red[4];
  int row = blockIdx.x;
  int tid = threadIdx.x, lane = tid & 63, w = tid >> 6;
  const u16* yr = yg + (size_t)row * 4096;
  float vals[16];
  float ss = 0.f;
#pragma unroll
  for (int i = 0; i < 2; ++i) {
    u16x8 v = *(const u16x8*)&yr[(i * 256 + tid) * 8];
#pragma unroll
    for (int j = 0; j < 8; ++j) { float f = bf2f(v[j]); vals[i * 8 + j] = f; ss += f * f; }
  }
#pragma unroll
  for (int off = 32; off > 0; off >>= 1) ss += __shfl_down(ss, off, 64);
  if (lane == 0) red[w] = ss;
  __syncthreads();
  float tot = red[0] + red[1] + red[2] + red[3];
  float scale = rsqrtf(tot * (1.0f / 4096.0f) + 1e-5f);
  u16* orow = out + (size_t)row * 4096;
#pragma unroll
  for (int i = 0; i < 2; ++i) {
    int base = (i * 256 + tid) * 8;
    u16x8 o;
#pragma unroll
    for (int j = 0; j < 8; ++j) o[j] = f2bf(vals[i * 8 + j] * scale * nw[base + j]);
    *(u16x8*)&orow[base] = o;
  }
}

// ---------------------------------------------------------------------------
extern "C" void kernel_launch(void* const* d_in, const int* in_sizes, int n_in,
                              void* d_out, int out_size, void* d_ws, size_t ws_size,
                              hipStream_t stream) {
  const float* u       = (const float*)d_in[0];
  const float* W_in    = (const float*)d_in[1];
  const float* conv_w  = (const float*)d_in[2];
  const float* conv_b  = (const float*)d_in[3];
  const float* dt_bias = (const float*)d_in[4];
  const float* A_log   = (const float*)d_in[5];
  const float* D_par   = (const float*)d_in[6];
  const float* norm_w  = (const float*)d_in[7];
  const float* W_out   = (const float*)d_in[8];
  float* out = (float*)d_out;

  auto rnd = [](size_t x) { return (x + 255) & ~(size_t)255; };
  size_t persist_small = rnd((size_t)524288 * 4) + rnd((size_t)3 * 4352 * 2) +
                         rnd((size_t)4096 * 4);
  size_t persist_w = rnd((size_t)17432576 * 2) + rnd((size_t)8388608 * 2);
  auto seg_bytes = [&](size_t L) {
    return rnd(L * 4096) + rnd(L * 8192) + rnd(L * 8832) + rnd(L * 8704) +
           rnd(L * 16384) + rnd(L * 256) + rnd(L * 256);
  };
  const int cands[6] = {4096, 2048, 1024, 512, 256, 128};
  int Ls = 0;
  bool f32w = false;
  for (int ci = 0; ci < 6 && Ls == 0; ++ci)   // tier 1: bf16 weight copies
    if (persist_small + persist_w + seg_bytes(cands[ci]) <= ws_size) Ls = cands[ci];
  if (Ls == 0) {                               // tier 2: f32 weights in GEMM
    f32w = true;
    for (int ci = 0; ci < 6 && Ls == 0; ++ci)
      if (persist_small + seg_bytes(cands[ci]) <= ws_size) Ls = cands[ci];
  }
  if (Ls == 0) return;  // ws < ~8 MB -> clean fail (diagnostic)

  char* ws = (char*)d_ws;
  size_t off = 0;
  auto alloc = [&](size_t bytes) { void* p = ws + off; off += (bytes + 255) & ~(size_t)255; return p; };
  u16* win_bf = nullptr; u16* wout_bf = nullptr;
  if (!f32w) {
    win_bf  = (u16*)alloc((size_t)17432576 * 2);
    wout_bf = (u16*)alloc((size_t)8388608 * 2);
  }
  float* carry   = (float*)alloc((size_t)524288 * 4);     // [h][p][n] f32
  u16*   tail    = (u16*)alloc((size_t)3 * 4352 * 2);
  float* alast   = (float*)alloc((size_t)4096 * 4);
  u16*   u_bf    = (u16*)alloc((size_t)Ls * 4096);
  u16*   zbuf    = (u16*)alloc((size_t)Ls * 8192);
  u16*   xdt     = (u16*)alloc((size_t)Ls * 8832);
  u16*   xbc     = (u16*)alloc((size_t)Ls * 8704);
  u16*   states  = (u16*)alloc((size_t)Ls * 16384);
  float* dtp     = (float*)alloc((size_t)Ls * 256);
  float* acs     = (float*)alloc((size_t)Ls * 256);
  u16*   ybuf    = xdt;            // alias: xdt dead after conv+save_tail
  u16*   ybf     = (u16*)states;   // alias: states dead after ssd_inter

  if (!f32w) {
    cast_bf<<<17024, 256, 0, stream>>>(W_in, win_bf, 17432576L);
    cast_bf<<<8192, 256, 0, stream>>>(W_out, wout_bf, 8388608L);
  }

  const int Cn = Ls / 64;
  const int S = 4096 / Ls;
  for (int b = 0; b < 2; ++b) {
    zero_f32<<<2048, 256, 0, stream>>>(carry, 524288);
    zero_f32<<<26, 256, 0, stream>>>((float*)tail, 6528);
    for (int s = 0; s < S; ++s) {
      size_t grow = (size_t)b * 4096 + (size_t)s * Ls;  // global row
      cast_bf<<<Ls * 2, 256, 0, stream>>>(u + grow * 2048, u_bf, (long)Ls * 2048);
      if (!f32w)
        gemm_zx<false><<<(Ls / 128) * 67, 256, 0, stream>>>(u_bf, win_bf, nullptr, zbuf, xdt, Ls, 8512, 2048, 67);
      else
        gemm_zx<true><<<(Ls / 128) * 67, 256, 0, stream>>>(u_bf, nullptr, W_in, zbuf, xdt, Ls, 8512, 2048, 67);
      dt_cs_kernel<<<Cn, 64, 0, stream>>>(xdt, dt_bias, A_log, dtp, acs, alast);
      conv_silu<<<Ls, 256, 0, stream>>>(xdt, tail, conv_w, conv_b, xbc);
      save_tail<<<1, 256, 0, stream>>>(xdt, tail, Ls);
      ssd_intra<<<dim3(64, Cn), 256, 0, stream>>>(xbc, dtp, acs, ybuf, states);
      state_scan<<<dim3(4, 64), 256, 0, stream>>>(states, alast, carry, Cn);
      ssd_inter<<<dim3(64, Cn), 256, 0, stream>>>(xbc, states, acs, zbuf, D_par, ybuf);
      rmsnorm_bf<<<Ls, 256, 0, stream>>>(ybuf, norm_w, ybf);
      if (!f32w)
        gemm_bt<false><<<(Ls / 128) * 16, 256, 0, stream>>>(ybf, wout_bf, nullptr, out + grow * 2048, Ls, 2048, 4096, 16);
      else
        gemm_bt<true><<<(Ls / 128) * 16, 256, 0, stream>>>(ybf, nullptr, W_out, out + grow * 2048, Ls, 2048, 4096, 16);
    }
  }
}